// Round 1
// baseline (1598.947 us; speedup 1.0000x reference)
//
#include <hip/hip_runtime.h>
#include <hip/hip_bf16.h>

#define DEV __device__ __forceinline__

typedef __attribute__((ext_vector_type(8))) __bf16 bf16x8;
typedef __attribute__((ext_vector_type(4))) float f32x4;

DEV unsigned short f2bf(float f) {
  unsigned u = __builtin_bit_cast(unsigned, f);
  u = (u + 0x7fffu + ((u >> 16) & 1u)) >> 16;
  return (unsigned short)u;
}
DEV float bf2f(unsigned short h) {
  unsigned u = ((unsigned)h) << 16;
  return __builtin_bit_cast(float, u);
}

// async global->LDS, 16B per lane; LDS dest = wave-uniform base + lane*16
DEV void gload16(const void* g, void* l) {
  __builtin_amdgcn_global_load_lds((__attribute__((address_space(1))) void*)(g),
                                   (__attribute__((address_space(3))) void*)(l),
                                   16, 0, 0);
}

// ---------------- transpose + fp32->bf16 cast: dst[n][k] = src[k][n] ----------------
__global__ __launch_bounds__(256) void k_transpose(const float* __restrict__ src,
                                                   unsigned short* __restrict__ dst,
                                                   int R, int C, long sB, long dB) {
  src += (long)blockIdx.z * sB;
  dst += (long)blockIdx.z * dB;
  __shared__ float tile[32][33];
  int tx = threadIdx.x & 31, ty = threadIdx.x >> 5;
  int c0 = blockIdx.x * 32, r0 = blockIdx.y * 32;
#pragma unroll
  for (int rr = ty; rr < 32; rr += 8) tile[rr][tx] = src[(long)(r0 + rr) * C + c0 + tx];
  __syncthreads();
#pragma unroll
  for (int cc = ty; cc < 32; cc += 8)
    dst[(long)(c0 + cc) * R + r0 + tx] = f2bf(tile[tx][cc]);
}

// ---------------- embed gather + LN1 ----------------
__global__ __launch_bounds__(256) void k_embed_ln(const int* __restrict__ ids,
                                                  const float* __restrict__ emb,
                                                  const float* __restrict__ g,
                                                  const float* __restrict__ b,
                                                  float* __restrict__ x, float* __restrict__ h) {
  int t = blockIdx.x, tid = threadIdx.x;
  long base = (long)ids[t] * 1024;
  float4 v = ((const float4*)(emb + base))[tid];
  float s = v.x + v.y + v.z + v.w;
  float ss = v.x * v.x + v.y * v.y + v.z * v.z + v.w * v.w;
  for (int o = 32; o; o >>= 1) { s += __shfl_xor(s, o); ss += __shfl_xor(ss, o); }
  __shared__ float rs[4], rss[4];
  int wv = tid >> 6;
  if ((tid & 63) == 0) { rs[wv] = s; rss[wv] = ss; }
  __syncthreads();
  s = rs[0] + rs[1] + rs[2] + rs[3];
  ss = rss[0] + rss[1] + rss[2] + rss[3];
  float mu = s * (1.f / 1024.f);
  float rstd = rsqrtf(ss * (1.f / 1024.f) - mu * mu + 1e-5f);
  float4 gg = ((const float4*)g)[tid];
  float4 bb = ((const float4*)b)[tid];
  float4 o4;
  o4.x = (v.x - mu) * rstd * gg.x + bb.x;
  o4.y = (v.y - mu) * rstd * gg.y + bb.y;
  o4.z = (v.z - mu) * rstd * gg.z + bb.z;
  o4.w = (v.w - mu) * rstd * gg.w + bb.w;
  ((float4*)(x + (long)t * 1024))[tid] = v;
  ((float4*)(h + (long)t * 1024))[tid] = o4;
}

// ---------------- v = h @ Wv  (2048x1024 @ 1024x64) ----------------
__global__ __launch_bounds__(64) void k_vgemm(const float* __restrict__ h,
                                              const float* __restrict__ Wv,
                                              float* __restrict__ v) {
  int j = threadIdx.x;
  int b = blockIdx.x * 16;
  float acc[16];
#pragma unroll
  for (int tt = 0; tt < 16; tt++) acc[tt] = 0.f;
  for (int k = 0; k < 1024; k++) {
    float wv = Wv[k * 64 + j];
#pragma unroll
    for (int tt = 0; tt < 16; tt++) acc[tt] += h[(long)(b + tt) * 1024 + k] * wv;
  }
#pragma unroll
  for (int tt = 0; tt < 16; tt++) v[(long)(b + tt) * 64 + j] = acc[tt];
}

// ---------------- Wo_eff[d][j] = sum_h Wo[h*64+d][j] ----------------
__global__ __launch_bounds__(256) void k_woeff(const float* __restrict__ Wo,
                                               float* __restrict__ woeff) {
  int i = blockIdx.x * 256 + threadIdx.x;
  int d = i >> 10, c = i & 1023;
  float s = 0.f;
#pragma unroll
  for (int hh = 0; hh < 16; hh++) s += Wo[(long)(hh * 64 + d) * 1024 + c];
  woeff[i] = s;
}

// ---------------- x2 = x + v @ Wo_eff ; t = LN2(x2) ----------------
__global__ __launch_bounds__(256) void k_attn_ln2(const float* __restrict__ x,
                                                  const float* __restrict__ v,
                                                  const float* __restrict__ woeff,
                                                  const float* __restrict__ g,
                                                  const float* __restrict__ b,
                                                  float* __restrict__ x2,
                                                  float* __restrict__ t32,
                                                  unsigned short* __restrict__ tbf) {
  int t = blockIdx.x, tid = threadIdx.x;
  __shared__ float vr[64];
  __shared__ float rs[4], rss[4];
  if (tid < 64) vr[tid] = v[t * 64 + tid];
  __syncthreads();
  float4 a = ((const float4*)(x + (long)t * 1024))[tid];
  float4 acc = {0.f, 0.f, 0.f, 0.f};
#pragma unroll 16
  for (int d = 0; d < 64; d++) {
    float4 w = ((const float4*)(woeff + d * 1024))[tid];
    float vd = vr[d];
    acc.x += vd * w.x; acc.y += vd * w.y; acc.z += vd * w.z; acc.w += vd * w.w;
  }
  a.x += acc.x; a.y += acc.y; a.z += acc.z; a.w += acc.w;
  ((float4*)(x2 + (long)t * 1024))[tid] = a;
  float s = a.x + a.y + a.z + a.w;
  float ss = a.x * a.x + a.y * a.y + a.z * a.z + a.w * a.w;
  for (int o = 32; o; o >>= 1) { s += __shfl_xor(s, o); ss += __shfl_xor(ss, o); }
  int wv = tid >> 6;
  if ((tid & 63) == 0) { rs[wv] = s; rss[wv] = ss; }
  __syncthreads();
  s = rs[0] + rs[1] + rs[2] + rs[3];
  ss = rss[0] + rss[1] + rss[2] + rss[3];
  float mu = s * (1.f / 1024.f);
  float rstd = rsqrtf(ss * (1.f / 1024.f) - mu * mu + 1e-5f);
  float4 gg = ((const float4*)g)[tid];
  float4 bb = ((const float4*)b)[tid];
  float4 o4;
  o4.x = (a.x - mu) * rstd * gg.x + bb.x;
  o4.y = (a.y - mu) * rstd * gg.y + bb.y;
  o4.z = (a.z - mu) * rstd * gg.z + bb.z;
  o4.w = (a.w - mu) * rstd * gg.w + bb.w;
  ((float4*)(t32 + (long)t * 1024))[tid] = o4;
  ushort4 ob;
  ob.x = f2bf(o4.x); ob.y = f2bf(o4.y); ob.z = f2bf(o4.z); ob.w = f2bf(o4.w);
  ((ushort4*)(tbf + (long)t * 1024))[tid] = ob;
}

// ---------------- router: logits -> top8 -> normalized softmax weights ----------------
__global__ __launch_bounds__(64) void k_router(const float* __restrict__ t32,
                                               const float* __restrict__ Wr,
                                               const float* __restrict__ br,
                                               int* __restrict__ ridx, float* __restrict__ rw) {
  int t = blockIdx.x, lane = threadIdx.x;
  float acc = -1e30f;
  if (lane < 32) {
    float s = 0.f;
    const float* tr = t32 + (long)t * 1024;
#pragma unroll 8
    for (int k = 0; k < 1024; k++) s += tr[k] * Wr[k * 32 + lane];
    acc = s + br[lane];
  }
  float cur = acc, top0 = 0.f, denom = 0.f, my_e = 0.f;
  int my_i = 0;
#pragma unroll
  for (int r = 0; r < 8; r++) {
    float v = cur;
    int bi = lane;
    for (int o = 32; o; o >>= 1) {
      float ov = __shfl_xor(v, o);
      int oi = __shfl_xor(bi, o);
      if (ov > v || (ov == v && oi < bi)) { v = ov; bi = oi; }
    }
    if (r == 0) top0 = v;
    float e = __expf(v - top0);
    denom += e;
    if (lane == r) { my_i = bi; my_e = e; }
    if (lane == bi) cur = -1e30f;
  }
  if (lane < 8) {
    ridx[t * 8 + lane] = my_i;
    rw[t * 8 + lane] = my_e / denom;
  }
}

// ---------------- bucket (token,expert) pairs into 128-padded per-expert tiles --------
__global__ __launch_bounds__(256) void k_build(const int* __restrict__ ridx,
                                               const float* __restrict__ rw,
                                               int* __restrict__ tok_of,
                                               int* __restrict__ slot_of,
                                               int* __restrict__ tile_e) {
  __shared__ int cnt[32], base_slot[32], cur[32];
  int tid = threadIdx.x;
  if (tid < 32) { cnt[tid] = 0; cur[tid] = 0; }
  __syncthreads();
  for (int i = tid; i < 16384; i += 256) atomicAdd(&cnt[ridx[i]], 1);
  __syncthreads();
  if (tid == 0) {
    int tile = 0;
    for (int e = 0; e < 32; e++) {
      base_slot[e] = tile * 128;
      int nt = (cnt[e] + 127) >> 7;
      for (int j = 0; j < nt; j++) tile_e[tile++] = e;
    }
    for (; tile < 160; tile++) tile_e[tile] = -1;
  }
  __syncthreads();
  for (int s = tid; s < 20480; s += 256) tok_of[s] = 0;  // pad rows -> token 0 (safe gather)
  __syncthreads();
  for (int i = tid; i < 16384; i += 256) {
    int e = ridx[i];
    int pos = atomicAdd(&cur[e], 1);
    int slot = base_slot[e] + pos;
    tok_of[slot] = i >> 3;
    slot_of[i] = slot;
  }
  (void)rw;
}

// ---------------- m97-style bf16 MFMA GEMM: C = A @ BT^T (+bias)(silu?) --------------
// A: MxK bf16 (row-major, stride lda). BT: NxK bf16. 128x128 tile, BK=32, 4 waves.
// MOE: blockIdx.y = tile index; expert from tile_e; A rows gathered via rowmap (or identity).
template <int SILU, int OBF16, int MOE>
__global__ __launch_bounds__(256) void k_gemm(const unsigned short* __restrict__ A, long aStride,
                                              int lda, const unsigned short* __restrict__ BT,
                                              long bStride, const float* __restrict__ bias,
                                              int biasStride, void* __restrict__ Cv, long cStride,
                                              int ldc, int K, const int* __restrict__ rowmap,
                                              const int* __restrict__ tile_e) {
  __shared__ unsigned short As[4096];  // 128 rows x 32 k
  __shared__ unsigned short Bs[4096];
  int tid = threadIdx.x, lane = tid & 63, wave = tid >> 6;
  int n0 = blockIdx.x * 128;
  int row0 = blockIdx.y * 128;
  unsigned short* Cb = (unsigned short*)Cv;
  float* Cf = (float*)Cv;
  if (MOE) {
    int e = tile_e[blockIdx.y];
    if (e < 0) return;
    BT += (long)e * bStride;
    bias += (long)e * biasStride;
  } else {
    int z = blockIdx.z;
    A += (long)z * aStride;
    BT += (long)z * bStride;
    bias += (long)z * biasStride;
    Cb += (long)z * cStride;
    Cf += (long)z * cStride;
  }
  const unsigned short* gA[2];
  const unsigned short* gB[2];
  char* dA[2];
  char* dB[2];
  int colb = (lane & 3) * 8;
#pragma unroll
  for (int i = 0; i < 2; i++) {
    int rl = i * 64 + wave * 16 + (lane >> 2);
    int ar;
    if (MOE) ar = rowmap ? rowmap[row0 + rl] : (row0 + rl);
    else ar = row0 + rl;
    gA[i] = A + (long)ar * lda + colb;
    gB[i] = BT + (long)(n0 + rl) * K + colb;
    dA[i] = (char*)As + i * 4096 + wave * 1024;
    dB[i] = (char*)Bs + i * 4096 + wave * 1024;
  }
  int l16 = lane & 15, quad = lane >> 4;
  int wm = wave >> 1, wn = wave & 1;
  const unsigned short* pa = As + (wm * 64 + l16) * 32 + quad * 8;
  const unsigned short* pb = Bs + (wn * 64 + l16) * 32 + quad * 8;
  f32x4 acc[4][4] = {};
  for (int kt = 0; kt < K; kt += 32) {
    __syncthreads();
    gload16(gA[0] + kt, dA[0]);
    gload16(gA[1] + kt, dA[1]);
    gload16(gB[0] + kt, dB[0]);
    gload16(gB[1] + kt, dB[1]);
    __syncthreads();
    bf16x8 av[4], bv[4];
#pragma unroll
    for (int i = 0; i < 4; i++) {
      av[i] = *(const bf16x8*)(pa + i * 512);
      bv[i] = *(const bf16x8*)(pb + i * 512);
    }
#pragma unroll
    for (int i = 0; i < 4; i++)
#pragma unroll
      for (int j = 0; j < 4; j++)
        acc[i][j] = __builtin_amdgcn_mfma_f32_16x16x32_bf16(av[i], bv[j], acc[i][j], 0, 0, 0);
  }
#pragma unroll
  for (int j = 0; j < 4; j++) {
    int col = n0 + wn * 64 + j * 16 + l16;
    float bb = bias[col];
#pragma unroll
    for (int i = 0; i < 4; i++) {
#pragma unroll
      for (int r = 0; r < 4; r++) {
        int row = row0 + wm * 64 + i * 16 + quad * 4 + r;
        float v = acc[i][j][r] + bb;
        if (SILU) v = v / (1.f + __expf(-v));
        if (OBF16) Cb[(long)row * ldc + col] = f2bf(v);
        else Cf[(long)row * ldc + col] = v;
      }
    }
  }
}

// ---------------- xf = x2 + shared0 + shared1 + sum_k w_k * Y[slot_k] ----------------
__global__ __launch_bounds__(256) void k_fuse(const float* __restrict__ x2,
                                              const float* __restrict__ csh,
                                              const unsigned short* __restrict__ Y,
                                              const int* __restrict__ slot_of,
                                              const float* __restrict__ rw,
                                              unsigned short* __restrict__ xfbf) {
  int t = blockIdx.x, tid = threadIdx.x;
  __shared__ int sl[8];
  __shared__ float sw[8];
  if (tid < 8) {
    sl[tid] = slot_of[t * 8 + tid];
    sw[tid] = rw[t * 8 + tid];
  }
  __syncthreads();
  float4 a = ((const float4*)(x2 + (long)t * 1024))[tid];
  float4 c0 = ((const float4*)(csh + (long)t * 1024))[tid];
  float4 c1 = ((const float4*)(csh + (long)(2048 + t) * 1024))[tid];
  float ax = a.x + c0.x + c1.x, ay = a.y + c0.y + c1.y;
  float az = a.z + c0.z + c1.z, aw = a.w + c0.w + c1.w;
#pragma unroll
  for (int r = 0; r < 8; r++) {
    ushort4 y = ((const ushort4*)(Y + (long)sl[r] * 1024))[tid];
    float w = sw[r];
    ax += w * bf2f(y.x); ay += w * bf2f(y.y);
    az += w * bf2f(y.z); aw += w * bf2f(y.w);
  }
  ushort4 o;
  o.x = f2bf(ax); o.y = f2bf(ay); o.z = f2bf(az); o.w = f2bf(aw);
  ((ushort4*)(xfbf + (long)t * 1024))[tid] = o;
}

extern "C" void kernel_launch(void* const* d_in, const int* in_sizes, int n_in, void* d_out,
                              int out_size, void* d_ws, size_t ws_size, hipStream_t stream) {
  const int* ids = (const int*)d_in[0];
  const float* emb = (const float*)d_in[1];
  // d_in[2]=Wq, d_in[3]=Wk: dead (softmax over singleton axis == 1)
  const float* Wv = (const float*)d_in[4];
  const float* Wo = (const float*)d_in[5];
  const float* g1 = (const float*)d_in[6];
  const float* beta1 = (const float*)d_in[7];
  const float* g2 = (const float*)d_in[8];
  const float* beta2 = (const float*)d_in[9];
  const float* Wr = (const float*)d_in[10];
  const float* br = (const float*)d_in[11];
  const float* We1 = (const float*)d_in[12];
  const float* be1 = (const float*)d_in[13];
  const float* We2 = (const float*)d_in[14];
  const float* be2 = (const float*)d_in[15];
  const float* Ws1 = (const float*)d_in[16];
  const float* bs1 = (const float*)d_in[17];
  const float* Ws2 = (const float*)d_in[18];
  const float* bs2 = (const float*)d_in[19];
  const float* Wout = (const float*)d_in[20];
  const float* bout = (const float*)d_in[21];
  (void)in_sizes; (void)n_in; (void)out_size; (void)ws_size;

  char* w = (char*)d_ws;
  auto alloc = [&](size_t n) {
    char* p = w;
    w += (n + 255) & ~(size_t)255;
    return p;
  };
  unsigned short* We1T = (unsigned short*)alloc(32ull * 1024 * 1024 * 2);
  unsigned short* We2T = (unsigned short*)alloc(32ull * 1024 * 1024 * 2);
  unsigned short* Ws1T = (unsigned short*)alloc(2ull * 4096 * 1024 * 2);
  unsigned short* Ws2T = (unsigned short*)alloc(2ull * 4096 * 1024 * 2);
  unsigned short* WoutT = (unsigned short*)alloc(32000ull * 1024 * 2);
  float* x = (float*)alloc(2048ull * 1024 * 4);
  float* h = (float*)alloc(2048ull * 1024 * 4);
  float* v = (float*)alloc(2048ull * 64 * 4);
  float* woeff = (float*)alloc(64ull * 1024 * 4);
  float* x2 = (float*)alloc(2048ull * 1024 * 4);
  float* t32 = (float*)alloc(2048ull * 1024 * 4);
  unsigned short* tbf = (unsigned short*)alloc(2048ull * 1024 * 2);
  int* ridx = (int*)alloc(16384ull * 4);
  float* rw = (float*)alloc(16384ull * 4);
  int* tok_of = (int*)alloc(20480ull * 4);
  int* slot_of = (int*)alloc(16384ull * 4);
  int* tile_e = (int*)alloc(256ull * 4);
  unsigned short* Ush = (unsigned short*)alloc(2ull * 2048 * 4096 * 2);
  float* Csh = (float*)alloc(2ull * 2048 * 1024 * 4);
  unsigned short* Umoe = (unsigned short*)alloc(20480ull * 1024 * 2);
  unsigned short* Y = (unsigned short*)alloc(20480ull * 1024 * 2);
  unsigned short* xfbf = (unsigned short*)alloc(2048ull * 1024 * 2);

  dim3 B256(256);
  // weight prep: transpose + cast to bf16 N x K
  k_transpose<<<dim3(32, 32, 32), B256, 0, stream>>>(We1, We1T, 1024, 1024, 1024L * 1024, 1024L * 1024);
  k_transpose<<<dim3(32, 32, 32), B256, 0, stream>>>(We2, We2T, 1024, 1024, 1024L * 1024, 1024L * 1024);
  k_transpose<<<dim3(128, 32, 2), B256, 0, stream>>>(Ws1, Ws1T, 1024, 4096, 4096L * 1024, 4096L * 1024);
  k_transpose<<<dim3(32, 128, 2), B256, 0, stream>>>(Ws2, Ws2T, 4096, 1024, 4096L * 1024, 4096L * 1024);
  k_transpose<<<dim3(1000, 32, 1), B256, 0, stream>>>(Wout, WoutT, 1024, 32000, 0, 0);

  k_embed_ln<<<2048, B256, 0, stream>>>(ids, emb, g1, beta1, x, h);
  k_vgemm<<<128, 64, 0, stream>>>(h, Wv, v);
  k_woeff<<<256, B256, 0, stream>>>(Wo, woeff);
  k_attn_ln2<<<2048, B256, 0, stream>>>(x, v, woeff, g2, beta2, x2, t32, tbf);
  k_router<<<2048, 64, 0, stream>>>(t32, Wr, br, ridx, rw);
  k_build<<<1, B256, 0, stream>>>(ridx, rw, tok_of, slot_of, tile_e);

  // shared FFN (batched over NS=2): U = silu(t@Ws1+bs1) ; Csh = U@Ws2+bs2
  k_gemm<1, 1, 0><<<dim3(32, 16, 2), B256, 0, stream>>>(tbf, 0L, 1024, Ws1T, 4096L * 1024, bs1,
                                                        4096, Ush, 2048L * 4096, 4096, 1024,
                                                        nullptr, nullptr);
  k_gemm<0, 0, 0><<<dim3(8, 16, 2), B256, 0, stream>>>(Ush, 2048L * 4096, 4096, Ws2T, 1024L * 4096,
                                                       bs2, 1024, Csh, 2048L * 1024, 1024, 4096,
                                                       nullptr, nullptr);
  // MoE (top-8 sparse): gather-A GEMM1 + silu, then GEMM2 over slots
  k_gemm<1, 1, 1><<<dim3(8, 160, 1), B256, 0, stream>>>(tbf, 0L, 1024, We1T, 1024L * 1024, be1,
                                                        1024, Umoe, 0L, 1024, 1024, tok_of, tile_e);
  k_gemm<0, 1, 1><<<dim3(8, 160, 1), B256, 0, stream>>>(Umoe, 0L, 1024, We2T, 1024L * 1024, be2,
                                                        1024, Y, 0L, 1024, 1024, nullptr, tile_e);
  k_fuse<<<2048, B256, 0, stream>>>(x2, Csh, Y, slot_of, rw, xfbf);
  // logits = xf @ Wout + bout
  k_gemm<0, 0, 0><<<dim3(250, 16, 1), B256, 0, stream>>>(xfbf, 0L, 1024, WoutT, 0L, bout, 0,
                                                         (float*)d_out, 0L, 32000, 1024, nullptr,
                                                         nullptr);
}

// Round 2
// 1352.855 us; speedup vs baseline: 1.1819x; 1.1819x over previous
//
#include <hip/hip_runtime.h>
#include <hip/hip_bf16.h>

#define DEV __device__ __forceinline__

typedef __attribute__((ext_vector_type(8))) __bf16 bf16x8;
typedef __attribute__((ext_vector_type(4))) float f32x4;

DEV unsigned short f2bf(float f) {
  unsigned u = __builtin_bit_cast(unsigned, f);
  u = (u + 0x7fffu + ((u >> 16) & 1u)) >> 16;
  return (unsigned short)u;
}
DEV float bf2f(unsigned short h) {
  unsigned u = ((unsigned)h) << 16;
  return __builtin_bit_cast(float, u);
}

// async global->LDS, 16B per lane; LDS dest = wave-uniform base + lane*16
DEV void gload16(const void* g, void* l) {
  __builtin_amdgcn_global_load_lds((__attribute__((address_space(1))) void*)(g),
                                   (__attribute__((address_space(3))) void*)(l),
                                   16, 0, 0);
}

// ---------------- transpose + fp32->bf16 cast: dst[n][k] = src[k][n] ----------------
// 64x64 tile, float4 coalesced reads, ushort4 coalesced writes.
__global__ __launch_bounds__(256) void k_transpose(const float* __restrict__ src,
                                                   unsigned short* __restrict__ dst,
                                                   int R, int C, long sB, long dB) {
  src += (long)blockIdx.z * sB;
  dst += (long)blockIdx.z * dB;
  __shared__ float tile[64][65];
  int tx = threadIdx.x & 15, ty = threadIdx.x >> 4;  // 16 x 16
  int c0 = blockIdx.x * 64, r0 = blockIdx.y * 64;
#pragma unroll
  for (int rr = ty; rr < 64; rr += 16) {
    float4 v = *(const float4*)(src + (long)(r0 + rr) * C + c0 + tx * 4);
    tile[rr][tx * 4 + 0] = v.x;
    tile[rr][tx * 4 + 1] = v.y;
    tile[rr][tx * 4 + 2] = v.z;
    tile[rr][tx * 4 + 3] = v.w;
  }
  __syncthreads();
#pragma unroll
  for (int cc = ty; cc < 64; cc += 16) {
    ushort4 o;
    o.x = f2bf(tile[tx * 4 + 0][cc]);
    o.y = f2bf(tile[tx * 4 + 1][cc]);
    o.z = f2bf(tile[tx * 4 + 2][cc]);
    o.w = f2bf(tile[tx * 4 + 3][cc]);
    *(ushort4*)(dst + (long)(c0 + cc) * R + r0 + tx * 4) = o;
  }
}

// ---------------- embed gather + LN1 ----------------
__global__ __launch_bounds__(256) void k_embed_ln(const int* __restrict__ ids,
                                                  const float* __restrict__ emb,
                                                  const float* __restrict__ g,
                                                  const float* __restrict__ b,
                                                  float* __restrict__ x, float* __restrict__ h) {
  int t = blockIdx.x, tid = threadIdx.x;
  long base = (long)ids[t] * 1024;
  float4 v = ((const float4*)(emb + base))[tid];
  float s = v.x + v.y + v.z + v.w;
  float ss = v.x * v.x + v.y * v.y + v.z * v.z + v.w * v.w;
  for (int o = 32; o; o >>= 1) { s += __shfl_xor(s, o); ss += __shfl_xor(ss, o); }
  __shared__ float rs[4], rss[4];
  int wv = tid >> 6;
  if ((tid & 63) == 0) { rs[wv] = s; rss[wv] = ss; }
  __syncthreads();
  s = rs[0] + rs[1] + rs[2] + rs[3];
  ss = rss[0] + rss[1] + rss[2] + rss[3];
  float mu = s * (1.f / 1024.f);
  float rstd = rsqrtf(ss * (1.f / 1024.f) - mu * mu + 1e-5f);
  float4 gg = ((const float4*)g)[tid];
  float4 bb = ((const float4*)b)[tid];
  float4 o4;
  o4.x = (v.x - mu) * rstd * gg.x + bb.x;
  o4.y = (v.y - mu) * rstd * gg.y + bb.y;
  o4.z = (v.z - mu) * rstd * gg.z + bb.z;
  o4.w = (v.w - mu) * rstd * gg.w + bb.w;
  ((float4*)(x + (long)t * 1024))[tid] = v;
  ((float4*)(h + (long)t * 1024))[tid] = o4;
}

// ---------------- v = h @ Wv  (2048x1024 @ 1024x64), 4 tokens/block, wave per token ----
__global__ __launch_bounds__(256) void k_vgemm(const float* __restrict__ h,
                                               const float* __restrict__ Wv,
                                               float* __restrict__ v) {
  __shared__ float hs[4][1024];
  int tid = threadIdx.x;
  int t0 = blockIdx.x * 4;
#pragma unroll
  for (int i = 0; i < 4; i++) {
    int idx = tid + i * 256;
    ((float4*)hs)[idx] = ((const float4*)(h + (long)t0 * 1024))[idx];
  }
  __syncthreads();
  int wave = tid >> 6, lane = tid & 63;
  const float* hr = hs[wave];
  float acc = 0.f;
#pragma unroll 4
  for (int k = 0; k < 1024; k += 4) {
    float4 hv = *(const float4*)(hr + k);
    acc += hv.x * Wv[(k + 0) * 64 + lane] + hv.y * Wv[(k + 1) * 64 + lane] +
           hv.z * Wv[(k + 2) * 64 + lane] + hv.w * Wv[(k + 3) * 64 + lane];
  }
  v[(long)(t0 + wave) * 64 + lane] = acc;
}

// ---------------- Wo_eff[d][j] = sum_h Wo[h*64+d][j] ----------------
__global__ __launch_bounds__(256) void k_woeff(const float* __restrict__ Wo,
                                               float* __restrict__ woeff) {
  int i = blockIdx.x * 256 + threadIdx.x;
  int d = i >> 10, c = i & 1023;
  float s = 0.f;
#pragma unroll
  for (int hh = 0; hh < 16; hh++) s += Wo[(long)(hh * 64 + d) * 1024 + c];
  woeff[i] = s;
}

// ---------------- x2 = x + v @ Wo_eff ; t = LN2(x2) ----------------
__global__ __launch_bounds__(256) void k_attn_ln2(const float* __restrict__ x,
                                                  const float* __restrict__ v,
                                                  const float* __restrict__ woeff,
                                                  const float* __restrict__ g,
                                                  const float* __restrict__ b,
                                                  float* __restrict__ x2,
                                                  float* __restrict__ t32,
                                                  unsigned short* __restrict__ tbf) {
  int t = blockIdx.x, tid = threadIdx.x;
  __shared__ float vr[64];
  __shared__ float rs[4], rss[4];
  if (tid < 64) vr[tid] = v[t * 64 + tid];
  __syncthreads();
  float4 a = ((const float4*)(x + (long)t * 1024))[tid];
  float4 acc = {0.f, 0.f, 0.f, 0.f};
#pragma unroll 16
  for (int d = 0; d < 64; d++) {
    float4 w = ((const float4*)(woeff + d * 1024))[tid];
    float vd = vr[d];
    acc.x += vd * w.x; acc.y += vd * w.y; acc.z += vd * w.z; acc.w += vd * w.w;
  }
  a.x += acc.x; a.y += acc.y; a.z += acc.z; a.w += acc.w;
  ((float4*)(x2 + (long)t * 1024))[tid] = a;
  float s = a.x + a.y + a.z + a.w;
  float ss = a.x * a.x + a.y * a.y + a.z * a.z + a.w * a.w;
  for (int o = 32; o; o >>= 1) { s += __shfl_xor(s, o); ss += __shfl_xor(ss, o); }
  int wv = tid >> 6;
  if ((tid & 63) == 0) { rs[wv] = s; rss[wv] = ss; }
  __syncthreads();
  s = rs[0] + rs[1] + rs[2] + rs[3];
  ss = rss[0] + rss[1] + rss[2] + rss[3];
  float mu = s * (1.f / 1024.f);
  float rstd = rsqrtf(ss * (1.f / 1024.f) - mu * mu + 1e-5f);
  float4 gg = ((const float4*)g)[tid];
  float4 bb = ((const float4*)b)[tid];
  float4 o4;
  o4.x = (a.x - mu) * rstd * gg.x + bb.x;
  o4.y = (a.y - mu) * rstd * gg.y + bb.y;
  o4.z = (a.z - mu) * rstd * gg.z + bb.z;
  o4.w = (a.w - mu) * rstd * gg.w + bb.w;
  ((float4*)(t32 + (long)t * 1024))[tid] = o4;
  ushort4 ob;
  ob.x = f2bf(o4.x); ob.y = f2bf(o4.y); ob.z = f2bf(o4.z); ob.w = f2bf(o4.w);
  ((ushort4*)(tbf + (long)t * 1024))[tid] = ob;
}

// ---------------- router: 4 tokens/block, wave per token, 2-way K split ----------------
__global__ __launch_bounds__(256) void k_router(const float* __restrict__ t32,
                                                const float* __restrict__ Wr,
                                                const float* __restrict__ br,
                                                int* __restrict__ ridx, float* __restrict__ rw) {
  int wave = threadIdx.x >> 6, lane = threadIdx.x & 63;
  int t = blockIdx.x * 4 + wave;
  int n = lane & 31, half = lane >> 5;
  const float* tr = t32 + (long)t * 1024 + half * 512;
  const float* wr = Wr + (long)half * 512 * 32 + n;
  float s = 0.f;
#pragma unroll 4
  for (int k = 0; k < 512; k += 4) {
    float4 tv = *(const float4*)(tr + k);
    s += tv.x * wr[(k + 0) * 32] + tv.y * wr[(k + 1) * 32] + tv.z * wr[(k + 2) * 32] +
         tv.w * wr[(k + 3) * 32];
  }
  s += __shfl_xor(s, 32);
  float acc = (half == 0) ? s + br[n] : -1e30f;
  float cur = acc, top0 = 0.f, denom = 0.f, my_e = 0.f;
  int my_i = 0;
#pragma unroll
  for (int r = 0; r < 8; r++) {
    float v = cur;
    int bi = n;
    for (int o = 32; o; o >>= 1) {
      float ov = __shfl_xor(v, o);
      int oi = __shfl_xor(bi, o);
      if (ov > v || (ov == v && oi < bi)) { v = ov; bi = oi; }
    }
    if (r == 0) top0 = v;
    float e = __expf(v - top0);
    denom += e;
    if (lane == r) { my_i = bi; my_e = e; }
    if (half == 0 && n == bi) cur = -1e30f;
  }
  if (lane < 8) {
    ridx[t * 8 + lane] = my_i;
    rw[t * 8 + lane] = my_e / denom;
  }
}

// ---------------- bucket (token,expert) pairs into 128-padded per-expert tiles --------
__global__ __launch_bounds__(256) void k_build(const int* __restrict__ ridx,
                                               const float* __restrict__ rw,
                                               int* __restrict__ tok_of,
                                               int* __restrict__ slot_of,
                                               int* __restrict__ tile_e) {
  __shared__ int cnt[32], base_slot[32], cur[32];
  int tid = threadIdx.x;
  if (tid < 32) { cnt[tid] = 0; cur[tid] = 0; }
  __syncthreads();
  for (int i = tid; i < 16384; i += 256) atomicAdd(&cnt[ridx[i]], 1);
  __syncthreads();
  if (tid == 0) {
    int tile = 0;
    for (int e = 0; e < 32; e++) {
      base_slot[e] = tile * 128;
      int nt = (cnt[e] + 127) >> 7;
      for (int j = 0; j < nt; j++) tile_e[tile++] = e;
    }
    for (; tile < 160; tile++) tile_e[tile] = -1;
  }
  __syncthreads();
  for (int s = tid; s < 20480; s += 256) tok_of[s] = 0;  // pad rows -> token 0 (safe gather)
  __syncthreads();
  for (int i = tid; i < 16384; i += 256) {
    int e = ridx[i];
    int pos = atomicAdd(&cur[e], 1);
    int slot = base_slot[e] + pos;
    tok_of[slot] = i >> 3;
    slot_of[i] = slot;
  }
  (void)rw;
}

// ---------------- m97-style bf16 MFMA GEMM: C = A @ BT^T (+bias)(silu?) --------------
// A: MxK bf16 (row-major, stride lda). BT: NxK bf16. 128x128 tile, BK=32, 4 waves.
// MOE: blockIdx.y = tile index; expert from tile_e; A rows gathered via rowmap.
// SWAPXY: blockIdx.x = M-tile (fast), blockIdx.y = N-tile -> co-resident blocks share B.
// NT: nontemporal stores for streaming fp32 output (don't pollute L2/L3).
template <int SILU, int OBF16, int MOE, int SWAPXY, int NT>
__global__ __launch_bounds__(256) void k_gemm(const unsigned short* __restrict__ A, long aStride,
                                              int lda, const unsigned short* __restrict__ BT,
                                              long bStride, const float* __restrict__ bias,
                                              int biasStride, void* __restrict__ Cv, long cStride,
                                              int ldc, int K, const int* __restrict__ rowmap,
                                              const int* __restrict__ tile_e) {
  __shared__ unsigned short As[4096];  // 128 rows x 32 k
  __shared__ unsigned short Bs[4096];
  int tid = threadIdx.x, lane = tid & 63, wave = tid >> 6;
  int bx = SWAPXY ? blockIdx.y : blockIdx.x;
  int by = SWAPXY ? blockIdx.x : blockIdx.y;
  int n0 = bx * 128;
  int row0 = by * 128;
  unsigned short* Cb = (unsigned short*)Cv;
  float* Cf = (float*)Cv;
  if (MOE) {
    int e = tile_e[by];
    if (e < 0) return;
    BT += (long)e * bStride;
    bias += (long)e * biasStride;
  } else {
    int z = blockIdx.z;
    A += (long)z * aStride;
    BT += (long)z * bStride;
    bias += (long)z * biasStride;
    Cb += (long)z * cStride;
    Cf += (long)z * cStride;
  }
  const unsigned short* gA[2];
  const unsigned short* gB[2];
  char* dA[2];
  char* dB[2];
  int colb = (lane & 3) * 8;
#pragma unroll
  for (int i = 0; i < 2; i++) {
    int rl = i * 64 + wave * 16 + (lane >> 2);
    int ar;
    if (MOE) ar = rowmap ? rowmap[row0 + rl] : (row0 + rl);
    else ar = row0 + rl;
    gA[i] = A + (long)ar * lda + colb;
    gB[i] = BT + (long)(n0 + rl) * K + colb;
    dA[i] = (char*)As + i * 4096 + wave * 1024;
    dB[i] = (char*)Bs + i * 4096 + wave * 1024;
  }
  int l16 = lane & 15, quad = lane >> 4;
  int wm = wave >> 1, wn = wave & 1;
  const unsigned short* pa = As + (wm * 64 + l16) * 32 + quad * 8;
  const unsigned short* pb = Bs + (wn * 64 + l16) * 32 + quad * 8;
  f32x4 acc[4][4] = {};
  for (int kt = 0; kt < K; kt += 32) {
    __syncthreads();
    gload16(gA[0] + kt, dA[0]);
    gload16(gA[1] + kt, dA[1]);
    gload16(gB[0] + kt, dB[0]);
    gload16(gB[1] + kt, dB[1]);
    __syncthreads();
    bf16x8 av[4], bv[4];
#pragma unroll
    for (int i = 0; i < 4; i++) {
      av[i] = *(const bf16x8*)(pa + i * 512);
      bv[i] = *(const bf16x8*)(pb + i * 512);
    }
#pragma unroll
    for (int i = 0; i < 4; i++)
#pragma unroll
      for (int j = 0; j < 4; j++)
        acc[i][j] = __builtin_amdgcn_mfma_f32_16x16x32_bf16(av[i], bv[j], acc[i][j], 0, 0, 0);
  }
#pragma unroll
  for (int j = 0; j < 4; j++) {
    int col = n0 + wn * 64 + j * 16 + l16;
    float bb = bias[col];
#pragma unroll
    for (int i = 0; i < 4; i++) {
#pragma unroll
      for (int r = 0; r < 4; r++) {
        int row = row0 + wm * 64 + i * 16 + quad * 4 + r;
        float v = acc[i][j][r] + bb;
        if (SILU) v = v / (1.f + __expf(-v));
        if (OBF16) {
          Cb[(long)row * ldc + col] = f2bf(v);
        } else if (NT) {
          __builtin_nontemporal_store(v, &Cf[(long)row * ldc + col]);
        } else {
          Cf[(long)row * ldc + col] = v;
        }
      }
    }
  }
}

// ---------------- xf = x2 + shared0 + shared1 + sum_k w_k * Y[slot_k] ----------------
__global__ __launch_bounds__(256) void k_fuse(const float* __restrict__ x2,
                                              const float* __restrict__ csh,
                                              const unsigned short* __restrict__ Y,
                                              const int* __restrict__ slot_of,
                                              const float* __restrict__ rw,
                                              unsigned short* __restrict__ xfbf) {
  int t = blockIdx.x, tid = threadIdx.x;
  __shared__ int sl[8];
  __shared__ float sw[8];
  if (tid < 8) {
    sl[tid] = slot_of[t * 8 + tid];
    sw[tid] = rw[t * 8 + tid];
  }
  __syncthreads();
  float4 a = ((const float4*)(x2 + (long)t * 1024))[tid];
  float4 c0 = ((const float4*)(csh + (long)t * 1024))[tid];
  float4 c1 = ((const float4*)(csh + (long)(2048 + t) * 1024))[tid];
  float ax = a.x + c0.x + c1.x, ay = a.y + c0.y + c1.y;
  float az = a.z + c0.z + c1.z, aw = a.w + c0.w + c1.w;
#pragma unroll
  for (int r = 0; r < 8; r++) {
    ushort4 y = ((const ushort4*)(Y + (long)sl[r] * 1024))[tid];
    float w = sw[r];
    ax += w * bf2f(y.x); ay += w * bf2f(y.y);
    az += w * bf2f(y.z); aw += w * bf2f(y.w);
  }
  ushort4 o;
  o.x = f2bf(ax); o.y = f2bf(ay); o.z = f2bf(az); o.w = f2bf(aw);
  ((ushort4*)(xfbf + (long)t * 1024))[tid] = o;
}

extern "C" void kernel_launch(void* const* d_in, const int* in_sizes, int n_in, void* d_out,
                              int out_size, void* d_ws, size_t ws_size, hipStream_t stream) {
  const int* ids = (const int*)d_in[0];
  const float* emb = (const float*)d_in[1];
  // d_in[2]=Wq, d_in[3]=Wk: dead (softmax over singleton axis == 1)
  const float* Wv = (const float*)d_in[4];
  const float* Wo = (const float*)d_in[5];
  const float* g1 = (const float*)d_in[6];
  const float* beta1 = (const float*)d_in[7];
  const float* g2 = (const float*)d_in[8];
  const float* beta2 = (const float*)d_in[9];
  const float* Wr = (const float*)d_in[10];
  const float* br = (const float*)d_in[11];
  const float* We1 = (const float*)d_in[12];
  const float* be1 = (const float*)d_in[13];
  const float* We2 = (const float*)d_in[14];
  const float* be2 = (const float*)d_in[15];
  const float* Ws1 = (const float*)d_in[16];
  const float* bs1 = (const float*)d_in[17];
  const float* Ws2 = (const float*)d_in[18];
  const float* bs2 = (const float*)d_in[19];
  const float* Wout = (const float*)d_in[20];
  const float* bout = (const float*)d_in[21];
  (void)in_sizes; (void)n_in; (void)out_size; (void)ws_size;

  char* w = (char*)d_ws;
  auto alloc = [&](size_t n) {
    char* p = w;
    w += (n + 255) & ~(size_t)255;
    return p;
  };
  unsigned short* We1T = (unsigned short*)alloc(32ull * 1024 * 1024 * 2);
  unsigned short* We2T = (unsigned short*)alloc(32ull * 1024 * 1024 * 2);
  unsigned short* Ws1T = (unsigned short*)alloc(2ull * 4096 * 1024 * 2);
  unsigned short* Ws2T = (unsigned short*)alloc(2ull * 4096 * 1024 * 2);
  unsigned short* WoutT = (unsigned short*)alloc(32000ull * 1024 * 2);
  float* x = (float*)alloc(2048ull * 1024 * 4);
  float* h = (float*)alloc(2048ull * 1024 * 4);
  float* v = (float*)alloc(2048ull * 64 * 4);
  float* woeff = (float*)alloc(64ull * 1024 * 4);
  float* x2 = (float*)alloc(2048ull * 1024 * 4);
  float* t32 = (float*)alloc(2048ull * 1024 * 4);
  unsigned short* tbf = (unsigned short*)alloc(2048ull * 1024 * 2);
  int* ridx = (int*)alloc(16384ull * 4);
  float* rw = (float*)alloc(16384ull * 4);
  int* tok_of = (int*)alloc(20480ull * 4);
  int* slot_of = (int*)alloc(16384ull * 4);
  int* tile_e = (int*)alloc(256ull * 4);
  unsigned short* Ush = (unsigned short*)alloc(2ull * 2048 * 4096 * 2);
  float* Csh = (float*)alloc(2ull * 2048 * 1024 * 4);
  unsigned short* Umoe = (unsigned short*)alloc(20480ull * 1024 * 2);
  unsigned short* Y = (unsigned short*)alloc(20480ull * 1024 * 2);
  unsigned short* xfbf = (unsigned short*)alloc(2048ull * 1024 * 2);

  dim3 B256(256);
  // weight prep: transpose + cast to bf16 N x K (64x64 tiles)
  k_transpose<<<dim3(16, 16, 32), B256, 0, stream>>>(We1, We1T, 1024, 1024, 1024L * 1024, 1024L * 1024);
  k_transpose<<<dim3(16, 16, 32), B256, 0, stream>>>(We2, We2T, 1024, 1024, 1024L * 1024, 1024L * 1024);
  k_transpose<<<dim3(64, 16, 2), B256, 0, stream>>>(Ws1, Ws1T, 1024, 4096, 4096L * 1024, 4096L * 1024);
  k_transpose<<<dim3(16, 64, 2), B256, 0, stream>>>(Ws2, Ws2T, 4096, 1024, 4096L * 1024, 4096L * 1024);
  k_transpose<<<dim3(500, 16, 1), B256, 0, stream>>>(Wout, WoutT, 1024, 32000, 0, 0);

  k_embed_ln<<<2048, B256, 0, stream>>>(ids, emb, g1, beta1, x, h);
  k_vgemm<<<512, B256, 0, stream>>>(h, Wv, v);
  k_woeff<<<256, B256, 0, stream>>>(Wo, woeff);
  k_attn_ln2<<<2048, B256, 0, stream>>>(x, v, woeff, g2, beta2, x2, t32, tbf);
  k_router<<<512, B256, 0, stream>>>(t32, Wr, br, ridx, rw);
  k_build<<<1, B256, 0, stream>>>(ridx, rw, tok_of, slot_of, tile_e);

  // shared FFN (batched over NS=2): U = silu(t@Ws1+bs1) ; Csh = U@Ws2+bs2
  k_gemm<1, 1, 0, 0, 0><<<dim3(32, 16, 2), B256, 0, stream>>>(tbf, 0L, 1024, Ws1T, 4096L * 1024,
                                                              bs1, 4096, Ush, 2048L * 4096, 4096,
                                                              1024, nullptr, nullptr);
  k_gemm<0, 0, 0, 0, 0><<<dim3(8, 16, 2), B256, 0, stream>>>(Ush, 2048L * 4096, 4096, Ws2T,
                                                             1024L * 4096, bs2, 1024, Csh,
                                                             2048L * 1024, 1024, 4096, nullptr,
                                                             nullptr);
  // MoE (top-8 sparse): gather-A GEMM1 + silu, then GEMM2 over slots
  k_gemm<1, 1, 1, 0, 0><<<dim3(8, 160, 1), B256, 0, stream>>>(tbf, 0L, 1024, We1T, 1024L * 1024,
                                                              be1, 1024, Umoe, 0L, 1024, 1024,
                                                              tok_of, tile_e);
  k_gemm<0, 1, 1, 0, 0><<<dim3(8, 160, 1), B256, 0, stream>>>(Umoe, 0L, 1024, We2T, 1024L * 1024,
                                                              be2, 1024, Y, 0L, 1024, 1024,
                                                              nullptr, tile_e);
  k_fuse<<<2048, B256, 0, stream>>>(x2, Csh, Y, slot_of, rw, xfbf);
  // logits = xf @ Wout + bout  (M-tile fastest so co-resident blocks share B; NT stores)
  k_gemm<0, 0, 0, 1, 1><<<dim3(16, 250, 1), B256, 0, stream>>>(xfbf, 0L, 1024, WoutT, 0L, bout, 0,
                                                               (float*)d_out, 0L, 32000, 1024,
                                                               nullptr, nullptr);
}